// Round 1
// baseline (225.725 us; speedup 1.0000x reference)
//
#include <hip/hip_runtime.h>

// ---------------------------------------------------------------------------
// ANHPMultiHeadAttention: fused QKV projection + exp-scored causal attention
// B=8, S=1024, FEAT=HID=1024, H=8, DH=128.
//
// Pipeline (all bf16 MFMA, fp32 accumulate):
//   1. cast_x:       X fp32 [8192,1024] -> bf16
//   2. transpose_w:  Wq/Wk/Wv fp32 [K,N] -> bf16 W^T [N,K] (k-contiguous B-frags)
//   3. gemm_qkv:     Q,K -> [B,H,S,DH] bf16 ; V -> [B,H,DH,S] bf16 (transposed)
//   4. attn:         flash-style loop; non-standard softmax(exp(logits)+mask).
//      Since s' = exp(logit) in [~0.05, ~25], exp(s') fits fp32 -> NO online
//      max/rescale needed: accumulate l = sum exp(s'), O = sum exp(s')*v.
//      Masked (key>query) entries are exactly 0 (ref gets ~1e-55).
// ---------------------------------------------------------------------------

typedef __bf16 bf16x8 __attribute__((ext_vector_type(8)));
typedef float floatx4 __attribute__((ext_vector_type(4)));
typedef unsigned short u16;

#define RSCALE 0.08838834764831845f   // 1/sqrt(128)

__device__ __forceinline__ u16 f2b(float f) {       // fp32 -> bf16 bits, RNE
  union { float f; unsigned u; } v; v.f = f;
  return (u16)((v.u + 0x7FFFu + ((v.u >> 16) & 1u)) >> 16);
}

// async global->LDS, 16B per lane. LDS dst = wave-uniform base + lane*16.
__device__ __forceinline__ void gld_lds16(const void* g, void* l) {
  __builtin_amdgcn_global_load_lds(
      (const __attribute__((address_space(1))) unsigned*)g,
      (__attribute__((address_space(3))) unsigned*)l, 16, 0, 0);
}

#define MFMA16(a, b, c) __builtin_amdgcn_mfma_f32_16x16x32_bf16(a, b, c, 0, 0, 0)

// ---------------------------------------------------------------------------
// Kernel 1: cast queries fp32 -> bf16
// ---------------------------------------------------------------------------
__global__ __launch_bounds__(256) void cast_x_kernel(const float4* __restrict__ X,
                                                     u16* __restrict__ Xb) {
  unsigned i = blockIdx.x * 256u + threadIdx.x;   // 8192 blocks * 256 * 4 = 8M
  float4 v = X[i];
  ushort4 o;
  o.x = f2b(v.x); o.y = f2b(v.y); o.z = f2b(v.z); o.w = f2b(v.w);
  *reinterpret_cast<ushort4*>(Xb + 4u * i) = o;
}

// ---------------------------------------------------------------------------
// Kernel 2: transpose+cast W [K=1024][N=1024] fp32 -> Wt [N][K] bf16
// grid (32,32,3), block (32,8)
// ---------------------------------------------------------------------------
__global__ __launch_bounds__(256) void transpose_w_kernel(
    const float* __restrict__ Wq, const float* __restrict__ Wk,
    const float* __restrict__ Wv, u16* __restrict__ Wtb) {
  const float* W = (blockIdx.z == 0) ? Wq : (blockIdx.z == 1) ? Wk : Wv;
  u16* Wt = Wtb + (size_t)blockIdx.z * (1024u * 1024u);
  __shared__ u16 tile[32][33];
  const int x = threadIdx.x, y = threadIdx.y;
  const int kt = blockIdx.x * 32, nt = blockIdx.y * 32;
#pragma unroll
  for (int i = 0; i < 4; ++i)
    tile[y + 8 * i][x] = f2b(W[(size_t)(kt + y + 8 * i) * 1024 + nt + x]);
  __syncthreads();
#pragma unroll
  for (int i = 0; i < 4; ++i)
    Wt[(size_t)(nt + y + 8 * i) * 1024 + kt + x] = tile[x][y + 8 * i];
}

// ---------------------------------------------------------------------------
// Kernel 3: QKV GEMM. C[m,n] = sum_k X[m,k]*W[k,n] + bias[n]
// 128x128 tile, BK=32, 4 waves each 64x64 (4x4 of 16x16x32 MFMA).
// grid (64, 8, 3): z selects {Q,K,V}. Q,K stored [B,H,S,DH]; V stored [B,H,DH,S].
// ---------------------------------------------------------------------------
__global__ __launch_bounds__(256) void gemm_qkv_kernel(
    const u16* __restrict__ Xb, const u16* __restrict__ Wtb,
    const float* __restrict__ bq, const float* __restrict__ bk,
    const float* __restrict__ bv, u16* __restrict__ Qh, u16* __restrict__ Kh,
    u16* __restrict__ Vt) {
  const int mat = blockIdx.z;
  const u16* __restrict__ Wt = Wtb + (size_t)mat * (1024u * 1024u);
  const float* __restrict__ bias = (mat == 0) ? bq : (mat == 1) ? bk : bv;

  const int m0 = blockIdx.x * 128;   // row block in M = B*S = 8192
  const int n0 = blockIdx.y * 128;   // col block in N = 1024 (aligned to head)

  __shared__ u16 As[128 * 32];       // [m][k] 8KB
  __shared__ u16 Bs[128 * 32];       // [n][k] 8KB (from W^T)

  const int tid = threadIdx.x;
  const int wid = tid >> 6;
  const int lane = tid & 63;
  const int quad = lane >> 4;
  const int l16 = lane & 15;
  const int wm = (wid & 1) * 64;
  const int wn = (wid >> 1) * 64;

  const floatx4 z4 = {0.f, 0.f, 0.f, 0.f};
  floatx4 acc[4][4];
#pragma unroll
  for (int i = 0; i < 4; ++i)
#pragma unroll
    for (int j = 0; j < 4; ++j) acc[i][j] = z4;

  const int rbase = wid * 32;   // this wave stages rows [rbase, rbase+32)
  for (int k0 = 0; k0 < 1024; k0 += 32) {
    __syncthreads();   // prior iteration's LDS reads done
#pragma unroll
    for (int c = 0; c < 2; ++c) {
      // call covers 16 rows x 32k: lane L -> row L/4, 16B block L%4
      const int row = rbase + c * 16 + (lane >> 2);
      const int kk = k0 + (lane & 3) * 8;
      gld_lds16(Xb + (size_t)(m0 + row) * 1024 + kk, As + (rbase + c * 16) * 32);
      gld_lds16(Wt + (size_t)(n0 + row) * 1024 + kk, Bs + (rbase + c * 16) * 32);
    }
    __syncthreads();   // drains global_load_lds (vmcnt) per barrier semantics

    bf16x8 af[4], bfr[4];
#pragma unroll
    for (int i = 0; i < 4; ++i)
      af[i] = *(const bf16x8*)(As + (wm + i * 16 + l16) * 32 + quad * 8);
#pragma unroll
    for (int j = 0; j < 4; ++j)
      bfr[j] = *(const bf16x8*)(Bs + (wn + j * 16 + l16) * 32 + quad * 8);
#pragma unroll
    for (int i = 0; i < 4; ++i)
#pragma unroll
      for (int j = 0; j < 4; ++j) acc[i][j] = MFMA16(af[i], bfr[j], acc[i][j]);
  }

  // epilogue. C/D layout: col = l16, row = quad*4 + reg.
  const int b = m0 >> 10;          // batch (tiles never straddle: 1024 % 128 == 0)
  const int h = n0 >> 7;           // head  (BN=128 == DH)
  const int sbase = (m0 & 1023) + wm;
  float bv4[4];
#pragma unroll
  for (int j = 0; j < 4; ++j) bv4[j] = bias[n0 + wn + j * 16 + l16];

  if (mat < 2) {
    // out[((b*8+h)*1024 + s)*128 + d]
    u16* outp = (mat == 0 ? Qh : Kh) + (size_t)(b * 8 + h) * 1024 * 128;
#pragma unroll
    for (int i = 0; i < 4; ++i)
#pragma unroll
      for (int j = 0; j < 4; ++j) {
        const int d = wn + j * 16 + l16;
#pragma unroll
        for (int r = 0; r < 4; ++r) {
          const int s = sbase + i * 16 + quad * 4 + r;
          outp[(size_t)s * 128 + d] = f2b(acc[i][j][r] + bv4[j]);
        }
      }
  } else {
    // V^T: out[((b*8+h)*128 + d)*1024 + s]; 4 regs = 4 consecutive s -> 8B store
    u16* outp = Vt + (size_t)(b * 8 + h) * 128 * 1024;
#pragma unroll
    for (int i = 0; i < 4; ++i)
#pragma unroll
      for (int j = 0; j < 4; ++j) {
        const int d = wn + j * 16 + l16;
        const int s = sbase + i * 16 + quad * 4;
        ushort4 pk;
        pk.x = f2b(acc[i][j][0] + bv4[j]);
        pk.y = f2b(acc[i][j][1] + bv4[j]);
        pk.z = f2b(acc[i][j][2] + bv4[j]);
        pk.w = f2b(acc[i][j][3] + bv4[j]);
        *(ushort4*)(outp + (size_t)d * 1024 + s) = pk;
      }
  }
}

// ---------------------------------------------------------------------------
// Kernel 4: attention. grid (B*H=64, S/128=8), block 256 (4 waves x 32 q-rows).
// Qh,Kh: [B,H,S,DH] bf16; Vt: [B,H,DH,S] bf16; out: [B,S,HID] fp32.
// No online max (see header comment): l += exp(s'), O += exp(s')*v directly.
// ---------------------------------------------------------------------------
__global__ __launch_bounds__(256) void attn_kernel(const u16* __restrict__ Qh,
                                                   const u16* __restrict__ Kh,
                                                   const u16* __restrict__ Vt,
                                                   float* __restrict__ out) {
  const int bh = blockIdx.x;
  const int q0 = blockIdx.y * 128;
  const int tid = threadIdx.x;
  const int wid = tid >> 6;
  const int lane = tid & 63;
  const int quad = lane >> 4;
  const int l16 = lane & 15;

  __shared__ u16 Ks[32 * 128];      // [k_local][d], XOR-swizzled 16B blocks, 8KB
  __shared__ u16 Vs[128 * 32];      // [d][k_local] 8KB
  __shared__ u16 Ps[4 * 32 * 32];   // per-wave P round-trip (C->A layout), 8KB

  const u16* __restrict__ Qbase = Qh + (size_t)bh * 1024 * 128;
  const u16* __restrict__ Kbase = Kh + (size_t)bh * 1024 * 128;
  const u16* __restrict__ Vbase = Vt + (size_t)bh * 128 * 1024;

  const int qw = q0 + wid * 32;     // this wave's first q row (covers 32 rows)

  // Q A-frags straight from global: A[m=l16][k=quad*8+j], 16B per lane.
  bf16x8 qf[2][4];
#pragma unroll
  for (int mt = 0; mt < 2; ++mt)
#pragma unroll
    for (int c = 0; c < 4; ++c)
      qf[mt][c] = *(const bf16x8*)(Qbase + (size_t)(qw + mt * 16 + l16) * 128 +
                                   c * 32 + quad * 8);

  const floatx4 z4 = {0.f, 0.f, 0.f, 0.f};
  floatx4 o[2][8];
#pragma unroll
  for (int mt = 0; mt < 2; ++mt)
#pragma unroll
    for (int dt = 0; dt < 8; ++dt) o[mt][dt] = z4;
  float lacc[2][4] = {};

  const int kend = q0 + 128;        // causal: keys [0, q0+128)
  for (int k0 = 0; k0 < kend; k0 += 32) {
    __syncthreads();
    // stage K block [32 keys][128 d]: 2 calls/wave, 4 rows (256B) per call.
    // XOR swizzle: physical 16B-block p holds global block p ^ (row & 15).
#pragma unroll
    for (int c = 0; c < 2; ++c) {
      const int row = wid * 8 + c * 4 + (lane >> 4);
      const int gb = (lane & 15) ^ (row & 15);
      gld_lds16(Kbase + (size_t)(k0 + row) * 128 + gb * 8,
                Ks + (wid * 8 + c * 4) * 128);
    }
    // stage V^T block [128 d][32 keys]: 2 calls/wave, 16 rows (64B) per call.
#pragma unroll
    for (int c = 0; c < 2; ++c) {
      const int row = wid * 32 + c * 16 + (lane >> 2);
      const int kk = k0 + (lane & 3) * 8;
      gld_lds16(Vbase + (size_t)row * 1024 + kk, Vs + (wid * 32 + c * 16) * 32);
    }
    __syncthreads();

    // K B-frags: B[k=d][n=key] -> lane reads K[key=nt*16+l16][d chunk] (swizzled)
    bf16x8 kf[2][4];
#pragma unroll
    for (int nt = 0; nt < 2; ++nt)
#pragma unroll
      for (int c = 0; c < 4; ++c)
        kf[nt][c] = *(const bf16x8*)(Ks + (nt * 16 + l16) * 128 +
                                     (((c * 4 + quad) ^ l16) * 8));

#pragma unroll
    for (int mt = 0; mt < 2; ++mt) {
      floatx4 s0 = z4, s1 = z4;
#pragma unroll
      for (int c = 0; c < 4; ++c) {
        s0 = MFMA16(qf[mt][c], kf[0][c], s0);
        s1 = MFMA16(qf[mt][c], kf[1][c], s1);
      }
      // p = exp(exp(logit)) unmasked; exactly 0 masked (ref value ~1e-55).
#pragma unroll
      for (int r = 0; r < 4; ++r) {
        const int qrow = qw + mt * 16 + quad * 4 + r;
        const float e0 = fminf(__expf(s0[r] * RSCALE), 85.f);
        const float e1 = fminf(__expf(s1[r] * RSCALE), 85.f);
        const float p0 = (k0 + l16 > qrow) ? 0.f : __expf(e0);
        const float p1 = (k0 + 16 + l16 > qrow) ? 0.f : __expf(e1);
        lacc[mt][r] += p0 + p1;
        Ps[wid * 1024 + (mt * 16 + quad * 4 + r) * 32 + l16] = f2b(p0);
        Ps[wid * 1024 + (mt * 16 + quad * 4 + r) * 32 + 16 + l16] = f2b(p1);
      }
    }
    // P is per-wave private: only need LDS write->read ordering within wave.
    asm volatile("s_waitcnt lgkmcnt(0)" ::: "memory");

    bf16x8 pa[2];
#pragma unroll
    for (int mt = 0; mt < 2; ++mt)
      pa[mt] = *(const bf16x8*)(Ps + wid * 1024 + (mt * 16 + l16) * 32 + quad * 8);
#pragma unroll
    for (int dt = 0; dt < 8; ++dt) {
      const bf16x8 vf = *(const bf16x8*)(Vs + (dt * 16 + l16) * 32 + quad * 8);
      o[0][dt] = MFMA16(pa[0], vf, o[0][dt]);
      o[1][dt] = MFMA16(pa[1], vf, o[1][dt]);
    }
  }

  // reduce l across the 16 lanes of each quad (cols), once per kernel
  float linv[2][4];
#pragma unroll
  for (int mt = 0; mt < 2; ++mt)
#pragma unroll
    for (int r = 0; r < 4; ++r) {
      float s = lacc[mt][r];
      s += __shfl_xor(s, 1, 16);
      s += __shfl_xor(s, 2, 16);
      s += __shfl_xor(s, 4, 16);
      s += __shfl_xor(s, 8, 16);
      linv[mt][r] = 1.0f / s;
    }

  // out[b][s][h*128 + d] fp32
  float* outp = out + ((size_t)(bh >> 3) * 1024) * 1024 + (bh & 7) * 128;
#pragma unroll
  for (int mt = 0; mt < 2; ++mt)
#pragma unroll
    for (int dt = 0; dt < 8; ++dt)
#pragma unroll
      for (int r = 0; r < 4; ++r) {
        const int qrow = qw + mt * 16 + quad * 4 + r;
        outp[(size_t)qrow * 1024 + dt * 16 + l16] = o[mt][dt][r] * linv[mt][r];
      }
}

// ---------------------------------------------------------------------------
extern "C" void kernel_launch(void* const* d_in, const int* in_sizes, int n_in,
                              void* d_out, int out_size, void* d_ws,
                              size_t ws_size, hipStream_t stream) {
  const float* X = (const float*)d_in[0];
  const float* Wq = (const float*)d_in[1];
  const float* bq = (const float*)d_in[2];
  const float* Wk = (const float*)d_in[3];
  const float* bk = (const float*)d_in[4];
  const float* Wv = (const float*)d_in[5];
  const float* bv = (const float*)d_in[6];
  float* out = (float*)d_out;

  char* ws = (char*)d_ws;
  u16* Xb  = (u16*)(ws);                         // 16 MB  bf16 X
  u16* Wtb = (u16*)(ws + (16u << 20));           //  6 MB  bf16 W^T x3
  u16* Qh  = (u16*)(ws + (22u << 20));           // 16 MB  [B,H,S,DH]
  u16* Kh  = (u16*)(ws + (38u << 20));           // 16 MB  [B,H,S,DH]
  u16* Vt  = (u16*)(ws + (54u << 20));           // 16 MB  [B,H,DH,S]

  cast_x_kernel<<<8192, 256, 0, stream>>>((const float4*)X, Xb);
  dim3 gt(32, 32, 3), bt(32, 8);
  transpose_w_kernel<<<gt, bt, 0, stream>>>(Wq, Wk, Wv, Wtb);
  dim3 gg(64, 8, 3);
  gemm_qkv_kernel<<<gg, 256, 0, stream>>>(Xb, Wtb, bq, bk, bv, Qh, Kh, Vt);
  dim3 ga(64, 8);
  attn_kernel<<<ga, 256, 0, stream>>>(Qh, Kh, Vt, out);
}

// Round 2
// 204.739 us; speedup vs baseline: 1.1025x; 1.1025x over previous
//
#include <hip/hip_runtime.h>

// ---------------------------------------------------------------------------
// ANHPMultiHeadAttention: fused QKV projection + exp-scored causal attention
// B=8, S=1024, FEAT=HID=1024, H=8, DH=128.
//
// R2 changes vs R1:
//  - GEMM: BK=64 (128B LDS rows) + XOR-8 block swizzle -> <=2-way bank
//    conflicts (was 8-way), half the barriers.
//  - ATTN: BK=64; K double-buffered with prefetch issued AFTER the top
//    barrier; V single-buffered, drained by manual "s_waitcnt vmcnt(4);
//    s_barrier" that leaves the K-prefetch in flight (AITER-style partial
//    drain). All LDS tiles (Ks/Vs/Ps) XOR-swizzled -> conflict-free.
//  - ATTN: heavy q-tiles dispatch first (LPT) to fix 8x work imbalance.
// ---------------------------------------------------------------------------

typedef __bf16 bf16x8 __attribute__((ext_vector_type(8)));
typedef float floatx4 __attribute__((ext_vector_type(4)));
typedef unsigned short u16;

#define RSCALE 0.08838834764831845f   // 1/sqrt(128)

__device__ __forceinline__ u16 f2b(float f) {       // fp32 -> bf16 bits, RNE
  union { float f; unsigned u; } v; v.f = f;
  return (u16)((v.u + 0x7FFFu + ((v.u >> 16) & 1u)) >> 16);
}

// async global->LDS, 16B per lane. LDS dst = wave-uniform base + lane*16.
__device__ __forceinline__ void gld_lds16(const void* g, void* l) {
  __builtin_amdgcn_global_load_lds(
      (const __attribute__((address_space(1))) unsigned*)g,
      (__attribute__((address_space(3))) unsigned*)l, 16, 0, 0);
}

#define MFMA16(a, b, c) __builtin_amdgcn_mfma_f32_16x16x32_bf16(a, b, c, 0, 0, 0)

// ---------------------------------------------------------------------------
// Kernel 1: cast queries fp32 -> bf16
// ---------------------------------------------------------------------------
__global__ __launch_bounds__(256) void cast_x_kernel(const float4* __restrict__ X,
                                                     u16* __restrict__ Xb) {
  unsigned i = blockIdx.x * 256u + threadIdx.x;
  float4 v = X[i];
  ushort4 o;
  o.x = f2b(v.x); o.y = f2b(v.y); o.z = f2b(v.z); o.w = f2b(v.w);
  *reinterpret_cast<ushort4*>(Xb + 4u * i) = o;
}

// ---------------------------------------------------------------------------
// Kernel 2: transpose+cast W [K=1024][N=1024] fp32 -> Wt [N][K] bf16
// ---------------------------------------------------------------------------
__global__ __launch_bounds__(256) void transpose_w_kernel(
    const float* __restrict__ Wq, const float* __restrict__ Wk,
    const float* __restrict__ Wv, u16* __restrict__ Wtb) {
  const float* W = (blockIdx.z == 0) ? Wq : (blockIdx.z == 1) ? Wk : Wv;
  u16* Wt = Wtb + (size_t)blockIdx.z * (1024u * 1024u);
  __shared__ u16 tile[32][33];
  const int x = threadIdx.x, y = threadIdx.y;
  const int kt = blockIdx.x * 32, nt = blockIdx.y * 32;
#pragma unroll
  for (int i = 0; i < 4; ++i)
    tile[y + 8 * i][x] = f2b(W[(size_t)(kt + y + 8 * i) * 1024 + nt + x]);
  __syncthreads();
#pragma unroll
  for (int i = 0; i < 4; ++i)
    Wt[(size_t)(nt + y + 8 * i) * 1024 + kt + x] = tile[x][y + 8 * i];
}

// ---------------------------------------------------------------------------
// Kernel 3: QKV GEMM. 128x128 tile, BK=64, XOR-8 swizzled LDS (conflict-free).
// grid (64, 8, 3): z selects {Q,K,V}. Q,K stored [B,H,S,DH]; V [B,H,DH,S].
// ---------------------------------------------------------------------------
__global__ __launch_bounds__(256) void gemm_qkv_kernel(
    const u16* __restrict__ Xb, const u16* __restrict__ Wtb,
    const float* __restrict__ bq, const float* __restrict__ bk,
    const float* __restrict__ bv, u16* __restrict__ Qh, u16* __restrict__ Kh,
    u16* __restrict__ Vt) {
  const int mat = blockIdx.z;
  const u16* __restrict__ Wt = Wtb + (size_t)mat * (1024u * 1024u);
  const float* __restrict__ bias = (mat == 0) ? bq : (mat == 1) ? bk : bv;

  const int m0 = blockIdx.x * 128;
  const int n0 = blockIdx.y * 128;

  __shared__ u16 As[128 * 64];   // [m][k] 16KB, 128B rows, xor8-swizzled
  __shared__ u16 Bs[128 * 64];   // [n][k] 16KB

  const int tid = threadIdx.x;
  const int wid = tid >> 6;
  const int lane = tid & 63;
  const int quad = lane >> 4;
  const int l16 = lane & 15;
  const int l8 = lane & 7;
  const int wm = (wid & 1) * 64;
  const int wn = (wid >> 1) * 64;

  const floatx4 z4 = {0.f, 0.f, 0.f, 0.f};
  floatx4 acc[4][4];
#pragma unroll
  for (int i = 0; i < 4; ++i)
#pragma unroll
    for (int j = 0; j < 4; ++j) acc[i][j] = z4;

  // staging: each wave loads 32 rows of A and B; 1KB (8 rows) per call.
  const int srow = wid * 32;
  const int lrow = lane >> 3;            // 0..7 within call
  const int gblk = l8 ^ lrow;            // xor8 swizzle (row&7 == lrow)

  for (int k0 = 0; k0 < 1024; k0 += 64) {
    __syncthreads();
#pragma unroll
    for (int c = 0; c < 4; ++c) {
      const int row = srow + c * 8 + lrow;
      gld_lds16(Xb + (size_t)(m0 + row) * 1024 + k0 + gblk * 8,
                As + (srow + c * 8) * 64);
      gld_lds16(Wt + (size_t)(n0 + row) * 1024 + k0 + gblk * 8,
                Bs + (srow + c * 8) * 64);
    }
    __syncthreads();

#pragma unroll
    for (int c = 0; c < 2; ++c) {
      const int phys = ((c * 4 + quad) ^ (l16 & 7)) * 8;
      bf16x8 af[4], bfr[4];
#pragma unroll
      for (int i = 0; i < 4; ++i)
        af[i] = *(const bf16x8*)(As + (wm + i * 16 + l16) * 64 + phys);
#pragma unroll
      for (int j = 0; j < 4; ++j)
        bfr[j] = *(const bf16x8*)(Bs + (wn + j * 16 + l16) * 64 + phys);
#pragma unroll
      for (int i = 0; i < 4; ++i)
#pragma unroll
        for (int j = 0; j < 4; ++j) acc[i][j] = MFMA16(af[i], bfr[j], acc[i][j]);
    }
  }

  // epilogue. C/D layout: col = l16, row = quad*4 + reg.
  const int b = m0 >> 10;
  const int h = n0 >> 7;
  const int sbase = (m0 & 1023) + wm;
  float bv4[4];
#pragma unroll
  for (int j = 0; j < 4; ++j) bv4[j] = bias[n0 + wn + j * 16 + l16];

  if (mat < 2) {
    u16* outp = (mat == 0 ? Qh : Kh) + (size_t)(b * 8 + h) * 1024 * 128;
#pragma unroll
    for (int i = 0; i < 4; ++i)
#pragma unroll
      for (int j = 0; j < 4; ++j) {
        const int d = wn + j * 16 + l16;
#pragma unroll
        for (int r = 0; r < 4; ++r) {
          const int s = sbase + i * 16 + quad * 4 + r;
          outp[(size_t)s * 128 + d] = f2b(acc[i][j][r] + bv4[j]);
        }
      }
  } else {
    u16* outp = Vt + (size_t)(b * 8 + h) * 128 * 1024;
#pragma unroll
    for (int i = 0; i < 4; ++i)
#pragma unroll
      for (int j = 0; j < 4; ++j) {
        const int d = wn + j * 16 + l16;
        const int s = sbase + i * 16 + quad * 4;
        ushort4 pk;
        pk.x = f2b(acc[i][j][0] + bv4[j]);
        pk.y = f2b(acc[i][j][1] + bv4[j]);
        pk.z = f2b(acc[i][j][2] + bv4[j]);
        pk.w = f2b(acc[i][j][3] + bv4[j]);
        *(ushort4*)(outp + (size_t)d * 1024 + s) = pk;
      }
  }
}

// ---------------------------------------------------------------------------
// Kernel 4: attention. grid (B*H=64, 8), block 256 (4 waves x 32 q-rows).
// BK=64; K double-buffered (prefetch in flight across the mid barrier via
// manual s_waitcnt vmcnt(4)); V single-buffered; LDS fully swizzled.
// ---------------------------------------------------------------------------
__global__ __launch_bounds__(256) void attn_kernel(const u16* __restrict__ Qh,
                                                   const u16* __restrict__ Kh,
                                                   const u16* __restrict__ Vt,
                                                   float* __restrict__ out) {
  const int bh = blockIdx.x;
  const int qt = 7 - (int)blockIdx.y;     // heavy tiles dispatch first (LPT)
  const int q0 = qt * 128;
  const int tid = threadIdx.x;
  const int wid = tid >> 6;
  const int lane = tid & 63;
  const int quad = lane >> 4;
  const int l16 = lane & 15;
  const int l8 = lane & 7;

  __shared__ u16 Ks[2][64 * 128];   // [key][d] 256B rows, xor16-swizzled, 32KB
  __shared__ u16 Vs[128 * 64];      // [d][key] 128B rows, xor8-swizzled, 16KB
  __shared__ u16 Ps[4 * 32 * 64];   // per-wave [qrow][key], xor8, 16KB

  const u16* __restrict__ Qbase = Qh + (size_t)bh * 1024 * 128;
  const u16* __restrict__ Kbase = Kh + (size_t)bh * 1024 * 128;
  const u16* __restrict__ Vbase = Vt + (size_t)bh * 128 * 1024;

  const int qw = q0 + wid * 32;     // this wave's first q row (covers 32 rows)

  // Q A-frags straight from global: A[m=l16][k=quad*8+j], 16B per lane.
  bf16x8 qf[2][4];
#pragma unroll
  for (int mt = 0; mt < 2; ++mt)
#pragma unroll
    for (int c = 0; c < 4; ++c)
      qf[mt][c] = *(const bf16x8*)(Qbase + (size_t)(qw + mt * 16 + l16) * 128 +
                                   c * 32 + quad * 8);

  const floatx4 z4 = {0.f, 0.f, 0.f, 0.f};
  floatx4 o[2][8];
#pragma unroll
  for (int mt = 0; mt < 2; ++mt)
#pragma unroll
    for (int dt = 0; dt < 8; ++dt) o[mt][dt] = z4;
  float lacc[2][4] = {};

  const int n = (q0 + 128) >> 6;          // #64-key tiles: 2..16

  // --- staging helpers (inlined manually) ---
  // K tile: 64 rows x 256B; per wave 16 rows, 4 rows (1KB) per call.
  //   lane -> phys row wid*16+c*4+quad, phys block l16 holds g-block l16^(row&15)
  // V tile: 128 rows x 128B; per wave 32 rows, 8 rows (1KB) per call.
  //   lane -> phys row +lane>>3, phys block l8 holds g-block l8^(row&7)

  // prefetch K tile 0
  {
    const int kgb = l16 ^ quad;           // row&15 == c*4+quad, c=0 case below
#pragma unroll
    for (int c = 0; c < 4; ++c) {
      const int row = wid * 16 + c * 4 + quad;
      gld_lds16(Kbase + (size_t)row * 128 + (l16 ^ (c * 4 + quad)) * 8,
                Ks[0] + (wid * 16 + c * 4) * 128);
    }
    (void)kgb;
  }

  for (int i = 0; i < n; ++i) {
    const int k0 = i << 6;
    __syncthreads();   // drains K(i) prefetch; all waves done with Vs(i-1)

    // stage V(i) into the single Vs buffer (4 calls, oldest in vmcnt queue)
#pragma unroll
    for (int c = 0; c < 4; ++c) {
      const int row = wid * 32 + c * 8 + (lane >> 3);
      gld_lds16(Vbase + (size_t)row * 1024 + k0 + (l8 ^ (lane >> 3)) * 8,
                Vs + (wid * 32 + c * 8) * 64);
    }
    // prefetch K(i+1) into the other buffer (stays in flight past mid barrier)
    if (i + 1 < n) {
#pragma unroll
      for (int c = 0; c < 4; ++c) {
        const int row = wid * 16 + c * 4 + quad;
        gld_lds16(Kbase + (size_t)(k0 + 64 + row) * 128 +
                      (l16 ^ (c * 4 + quad)) * 8,
                  Ks[(i + 1) & 1] + (wid * 16 + c * 4) * 128);
      }
    }

    // ---- QK + exp + P (uses Ks[i&1], already drained by top barrier) ----
    const u16* Kbuf = Ks[i & 1];
#pragma unroll
    for (int nt = 0; nt < 4; ++nt) {
      bf16x8 kfc[4];
#pragma unroll
      for (int c = 0; c < 4; ++c)
        kfc[c] = *(const bf16x8*)(Kbuf + (nt * 16 + l16) * 128 +
                                  (((c * 4 + quad) ^ l16) * 8));
#pragma unroll
      for (int mt = 0; mt < 2; ++mt) {
        floatx4 s = z4;
#pragma unroll
        for (int c = 0; c < 4; ++c) s = MFMA16(qf[mt][c], kfc[c], s);
#pragma unroll
        for (int r = 0; r < 4; ++r) {
          const int qrow = qw + mt * 16 + quad * 4 + r;
          const int key = k0 + nt * 16 + l16;
          const float e = fminf(__expf(s[r] * RSCALE), 85.f);
          const float p = (key > qrow) ? 0.f : __expf(e);
          lacc[mt][r] += p;
          const int rowl = mt * 16 + quad * 4 + r;
          const int phys = (nt * 2 + (l16 >> 3)) ^ (rowl & 7);
          Ps[wid * 2048 + rowl * 64 + phys * 8 + (l16 & 7)] = f2b(p);
        }
      }
    }

    // mid barrier: own Ps writes done (lgkmcnt 0); V(i) drained (4 oldest vm
    // ops) while K(i+1) prefetch (4 newest) stays in flight.
    if (i + 1 < n)
      asm volatile("s_waitcnt vmcnt(4) lgkmcnt(0)\n\ts_barrier" ::: "memory");
    else
      asm volatile("s_waitcnt vmcnt(0) lgkmcnt(0)\n\ts_barrier" ::: "memory");

    // ---- PV ----
    bf16x8 pa[2][2];
#pragma unroll
    for (int mt = 0; mt < 2; ++mt)
#pragma unroll
      for (int ck = 0; ck < 2; ++ck)
        pa[mt][ck] = *(const bf16x8*)(Ps + wid * 2048 + (mt * 16 + l16) * 64 +
                                      (((ck * 4 + quad) ^ (l16 & 7)) * 8));
#pragma unroll
    for (int dt = 0; dt < 8; ++dt)
#pragma unroll
      for (int ck = 0; ck < 2; ++ck) {
        const bf16x8 vf = *(const bf16x8*)(Vs + (dt * 16 + l16) * 64 +
                                           (((ck * 4 + quad) ^ (l16 & 7)) * 8));
        o[0][dt] = MFMA16(pa[0][ck], vf, o[0][dt]);
        o[1][dt] = MFMA16(pa[1][ck], vf, o[1][dt]);
      }
  }

  // reduce l across the 16 lanes of each quad-row
  float linv[2][4];
#pragma unroll
  for (int mt = 0; mt < 2; ++mt)
#pragma unroll
    for (int r = 0; r < 4; ++r) {
      float s = lacc[mt][r];
      s += __shfl_xor(s, 1, 16);
      s += __shfl_xor(s, 2, 16);
      s += __shfl_xor(s, 4, 16);
      s += __shfl_xor(s, 8, 16);
      linv[mt][r] = 1.0f / s;
    }

  // out[b][s][h*128 + d] fp32
  float* outp = out + ((size_t)(bh >> 3) * 1024) * 1024 + (bh & 7) * 128;
#pragma unroll
  for (int mt = 0; mt < 2; ++mt)
#pragma unroll
    for (int dt = 0; dt < 8; ++dt)
#pragma unroll
      for (int r = 0; r < 4; ++r) {
        const int qrow = qw + mt * 16 + quad * 4 + r;
        outp[(size_t)qrow * 1024 + dt * 16 + l16] = o[mt][dt][r] * linv[mt][r];
      }
}

// ---------------------------------------------------------------------------
extern "C" void kernel_launch(void* const* d_in, const int* in_sizes, int n_in,
                              void* d_out, int out_size, void* d_ws,
                              size_t ws_size, hipStream_t stream) {
  const float* X = (const float*)d_in[0];
  const float* Wq = (const float*)d_in[1];
  const float* bq = (const float*)d_in[2];
  const float* Wk = (const float*)d_in[3];
  const float* bk = (const float*)d_in[4];
  const float* Wv = (const float*)d_in[5];
  const float* bv = (const float*)d_in[6];
  float* out = (float*)d_out;

  char* ws = (char*)d_ws;
  u16* Xb  = (u16*)(ws);                         // 16 MB  bf16 X
  u16* Wtb = (u16*)(ws + (16u << 20));           //  6 MB  bf16 W^T x3
  u16* Qh  = (u16*)(ws + (22u << 20));           // 16 MB  [B,H,S,DH]
  u16* Kh  = (u16*)(ws + (38u << 20));           // 16 MB  [B,H,S,DH]
  u16* Vt  = (u16*)(ws + (54u << 20));           // 16 MB  [B,H,DH,S]

  cast_x_kernel<<<8192, 256, 0, stream>>>((const float4*)X, Xb);
  dim3 gt(32, 32, 3), bt(32, 8);
  transpose_w_kernel<<<gt, bt, 0, stream>>>(Wq, Wk, Wv, Wtb);
  dim3 gg(64, 8, 3);
  gemm_qkv_kernel<<<gg, 256, 0, stream>>>(Xb, Wtb, bq, bk, bv, Qh, Kh, Vt);
  dim3 ga(64, 8);
  attn_kernel<<<ga, 256, 0, stream>>>(Qh, Kh, Vt, out);
}